// Round 1
// baseline (85.914 us; speedup 1.0000x reference)
//
#include <hip/hip_runtime.h>

#define HH 2048
#define WW 2048
#define KK 7
#define PADK 3
#define TILE 32
#define PADT (TILE + 6)      // 38
#define IN_STRIDE (PADT + 2) // 40, breaks pow2 bank alias
#define HS_STRIDE (TILE + 1) // 33

__global__ __launch_bounds__(256)
void UnfoldPlainFit_42477226558039_kernel(const float* __restrict__ x,
                                          float* __restrict__ out) {
    __shared__ float sIn[PADT][IN_STRIDE];   // 38 x 40 input tile (clamped)
    __shared__ float sHs[PADT][HS_STRIDE];   // horizontal plain sums
    __shared__ float sHx[PADT][HS_STRIDE];   // horizontal x-weighted sums

    const int tileR = blockIdx.y * TILE;
    const int tileC = blockIdx.x * TILE;
    const int tid = threadIdx.x;  // 0..255

    // ---- Stage 1: load 38x38 clamped input tile into LDS ----
    for (int idx = tid; idx < PADT * PADT; idx += 256) {
        int lr = idx / PADT;
        int lc = idx - lr * PADT;
        int gr = tileR - PADK + lr;
        int gc = tileC - PADK + lc;
        gr = max(0, min(HH - 1, gr));   // replication (edge) padding
        gc = max(0, min(WW - 1, gc));
        sIn[lr][lc] = x[(size_t)gr * WW + gc];
    }
    __syncthreads();

    // ---- Stage 2: horizontal sums per padded row ----
    // idx -> lr = idx>>5 (0..37), oc = idx&31 : consecutive lanes hit
    // consecutive LDS columns -> conflict-free.
    for (int idx = tid; idx < PADT * TILE; idx += 256) {
        int lr = idx >> 5;
        int oc = idx & 31;
        float s = 0.f, wx = 0.f;
#pragma unroll
        for (int j = 0; j < KK; ++j) {
            float v = sIn[lr][oc + j];
            s += v;
            wx += (float)(j - PADK) * v;
        }
        sHs[lr][oc] = s;
        sHx[lr][oc] = wx;
    }
    __syncthreads();

    // ---- Stage 3: vertical combine, 4 output pixels per thread ----
    const int oc = tid & 31;
    const int orBase = tid >> 5;  // 0..7
#pragma unroll
    for (int k = 0; k < 4; ++k) {
        int orr = orBase + k * 8;
        float c0 = 0.f, c1 = 0.f, c2 = 0.f;
#pragma unroll
        for (int i = 0; i < KK; ++i) {
            float hs = sHs[orr + i][oc];
            float hx = sHx[orr + i][oc];
            c2 += hs;
            c1 += (float)(i - PADK) * hs;
            c0 += hx;
        }
        c0 *= (1.0f / 196.0f);   // sum(x^2) over 7x7 grid = 196
        c1 *= (1.0f / 196.0f);
        c2 *= (1.0f / 49.0f);
        int r = tileR + orr;
        int c = tileC + oc;
        float* o = out + ((size_t)r * WW + c) * 3;
        o[0] = c0;
        o[1] = c1;
        o[2] = c2;
    }
}

extern "C" void kernel_launch(void* const* d_in, const int* in_sizes, int n_in,
                              void* d_out, int out_size, void* d_ws, size_t ws_size,
                              hipStream_t stream) {
    const float* x = (const float*)d_in[0];
    float* out = (float*)d_out;
    dim3 grid(WW / TILE, HH / TILE);  // 64 x 64 = 4096 blocks
    dim3 block(256);
    UnfoldPlainFit_42477226558039_kernel<<<grid, block, 0, stream>>>(x, out);
}